// Round 4
// baseline (182.734 us; speedup 1.0000x reference)
//
#include <hip/hip_runtime.h>

#define DIM   4096
#define BATCH 8192
// Two rows per 256-thread block (4 waves). Wave q owns quarter [1024q, 1024q+1024)
// of BOTH rows. Thread lane holds, per row r, e = 1024q + 256j + 4*lane + i
// (j=0..3, i=0..3) -> 2 x 4 float4 = 32 data VGPRs, two independent dep chains.
// Layer L pairs e with e^(1<<L); coeff index c = (4096 - (4096>>L)) + (e >> (L+1)).
//   L0..L1  : within float4 (i axis)           — register FMAs
//   L2..L7  : lane distance 1,2,4,8,16,32      — __shfl_xor (coeffs shared by both rows)
//   L8..L9  : register index j distance 1,2    — register FMAs
//   L10+L11 : cross-wave (q axis), FUSED into one 4-source combine — 1 barrier.
// LDS 32 KB -> 5 blocks/CU (62.5% occ); __launch_bounds__(256,5) caps VGPR at ~102
// (R1 lesson: never cap below the data working set — forces spill).

__device__ __forceinline__ void rot2(float& lo, float& hi, float a, float b) {
    float l = lo, h = hi;
    lo = fmaf(a, l,  b * h);   // top =  a*x0 + b*x1
    hi = fmaf(a, h, -b * l);   // bot = -b*x0 + a*x1
}

template<bool PACKED>
__device__ __forceinline__ float2 coef(const float* __restrict__ af,
                                       const float* __restrict__ bf,
                                       const float2* __restrict__ ab, int c) {
    if constexpr (PACKED) return ab[c];
    else                  return make_float2(af[c], bf[c]);
}

// Shuffle layer over both rows: M = lane-xor distance, JSH/LSH = coeff index shifts.
template<int M, int JSH, int LSH, bool PACKED>
__device__ __forceinline__ void shuf_layer(float4 (&v)[2][4], int lane, int base,
                                           const float* __restrict__ af,
                                           const float* __restrict__ bf,
                                           const float2* __restrict__ ab) {
    #pragma unroll
    for (int j = 0; j < 4; ++j) {
        const int c = base + (j << JSH) + (lane >> LSH);
        float2 q = coef<PACKED>(af, bf, ab, c);
        const float sb = (lane & M) ? -q.y : q.y;   // top: +b*partner ; bot: -b*partner
        #pragma unroll
        for (int r = 0; r < 2; ++r) {
            v[r][j].x = fmaf(q.x, v[r][j].x, sb * __shfl_xor(v[r][j].x, M, 64));
            v[r][j].y = fmaf(q.x, v[r][j].y, sb * __shfl_xor(v[r][j].y, M, 64));
            v[r][j].z = fmaf(q.x, v[r][j].z, sb * __shfl_xor(v[r][j].z, M, 64));
            v[r][j].w = fmaf(q.x, v[r][j].w, sb * __shfl_xor(v[r][j].w, M, 64));
        }
    }
}

template<bool PACKED>
__global__ __launch_bounds__(256, 5)
void bfly_kernel(const float* __restrict__ x,
                 const float* __restrict__ af,
                 const float* __restrict__ bf,
                 const float2* __restrict__ ab,
                 float* __restrict__ out) {
    const int lane = threadIdx.x & 63;
    const int q    = threadIdx.x >> 6;     // wave index = row quarter

    const float4* __restrict__ xr0 =
        reinterpret_cast<const float4*>(x + (size_t)(blockIdx.x * 2 + 0) * DIM) + q * 256;
    const float4* __restrict__ xr1 =
        reinterpret_cast<const float4*>(x + (size_t)(blockIdx.x * 2 + 1) * DIM) + q * 256;
    float4* __restrict__ or0 =
        reinterpret_cast<float4*>(out + (size_t)(blockIdx.x * 2 + 0) * DIM) + q * 256;
    float4* __restrict__ or1 =
        reinterpret_cast<float4*>(out + (size_t)(blockIdx.x * 2 + 1) * DIM) + q * 256;

    __shared__ float4 xch[2][4][4][64];   // [row][wave][j][lane] = 32 KB

    float4 v[2][4];
    #pragma unroll
    for (int j = 0; j < 4; ++j) v[0][j] = xr0[64 * j + lane];
    #pragma unroll
    for (int j = 0; j < 4; ++j) v[1][j] = xr1[64 * j + lane];

    // ---- L0 (bs=1): pairs (x,y),(z,w); c0 = 512q + 128j + 2*lane, c0+1 ----
    #pragma unroll
    for (int j = 0; j < 4; ++j) {
        float a0, b0, a1, b1;
        if constexpr (PACKED) {
            float4 p = reinterpret_cast<const float4*>(ab)[q * 256 + 64 * j + lane]; // (a0,b0,a1,b1)
            a0 = p.x; b0 = p.y; a1 = p.z; b1 = p.w;
        } else {
            const int c = 512 * q + 128 * j + 2 * lane;
            float2 aa = *reinterpret_cast<const float2*>(af + c);
            float2 bb = *reinterpret_cast<const float2*>(bf + c);
            a0 = aa.x; b0 = bb.x; a1 = aa.y; b1 = bb.y;
        }
        #pragma unroll
        for (int r = 0; r < 2; ++r) {
            rot2(v[r][j].x, v[r][j].y, a0, b0);
            rot2(v[r][j].z, v[r][j].w, a1, b1);
        }
    }

    // ---- L1 (bs=2): pairs (x,z),(y,w); c = 2048 + 256q + 64j + lane ----
    #pragma unroll
    for (int j = 0; j < 4; ++j) {
        float2 p = coef<PACKED>(af, bf, ab, 2048 + 256 * q + 64 * j + lane);
        #pragma unroll
        for (int r = 0; r < 2; ++r) {
            rot2(v[r][j].x, v[r][j].z, p.x, p.y);
            rot2(v[r][j].y, v[r][j].w, p.x, p.y);
        }
    }

    // ---- L2..L7: shuffle layers ----
    shuf_layer< 1, 5, 1, PACKED>(v, lane, 3072 + 128 * q, af, bf, ab);  // bs=4
    shuf_layer< 2, 4, 2, PACKED>(v, lane, 3584 +  64 * q, af, bf, ab);  // bs=8
    shuf_layer< 4, 3, 3, PACKED>(v, lane, 3840 +  32 * q, af, bf, ab);  // bs=16
    shuf_layer< 8, 2, 4, PACKED>(v, lane, 3968 +  16 * q, af, bf, ab);  // bs=32
    shuf_layer<16, 1, 5, PACKED>(v, lane, 4032 +   8 * q, af, bf, ab);  // bs=64
    shuf_layer<32, 0, 6, PACKED>(v, lane, 4064 +   4 * q, af, bf, ab);  // bs=128

    // ---- L8 (bs=256): pairs (0,1),(2,3); c = 4080 + 2q + k ----
    #pragma unroll
    for (int k = 0; k < 2; ++k) {
        float2 p = coef<PACKED>(af, bf, ab, 4080 + 2 * q + k);
        #pragma unroll
        for (int r = 0; r < 2; ++r) {
            rot2(v[r][2*k].x, v[r][2*k+1].x, p.x, p.y);
            rot2(v[r][2*k].y, v[r][2*k+1].y, p.x, p.y);
            rot2(v[r][2*k].z, v[r][2*k+1].z, p.x, p.y);
            rot2(v[r][2*k].w, v[r][2*k+1].w, p.x, p.y);
        }
    }
    // ---- L9 (bs=512): pairs (0,2),(1,3); c = 4088 + q ----
    {
        float2 p = coef<PACKED>(af, bf, ab, 4088 + q);
        #pragma unroll
        for (int r = 0; r < 2; ++r)
            #pragma unroll
            for (int j = 0; j < 2; ++j) {
                rot2(v[r][j].x, v[r][j+2].x, p.x, p.y);
                rot2(v[r][j].y, v[r][j+2].y, p.x, p.y);
                rot2(v[r][j].z, v[r][j+2].z, p.x, p.y);
                rot2(v[r][j].w, v[r][j+2].w, p.x, p.y);
            }
    }

    // ---- L10+L11 fused: one 4-source combine across waves, ONE barrier ----
    // u[q] = sum_{q'} W[q'] * v[q'] with W derived from theta(4092+h11'), theta(4093),
    // phi(4094). Using phi[h11][h11] = A always:
    //   w_own = A*aO ; w(q^1) = A*(h10? -bO : bO) ; w(q^2) = phX*aX ;
    //   w(q^3) = phX*(h10? -bX : bX) ; phX = h11 ? -B : B.
    {
        float2 c0 = coef<PACKED>(af, bf, ab, 4092);   // (a0,b0) for e11=0
        float2 c1 = coef<PACKED>(af, bf, ab, 4093);   // (a1,b1) for e11=1
        float2 c2 = coef<PACKED>(af, bf, ab, 4094);   // (A,B)
        const int h11 = q >> 1, h10 = q & 1;
        const float aO = h11 ? c1.x : c0.x, bO = h11 ? c1.y : c0.y;
        const float aX = h11 ? c0.x : c1.x, bX = h11 ? c0.y : c1.y;
        const float phX = h11 ? -c2.y : c2.y;
        const float w0 = c2.x * aO;                    // own
        const float w1 = c2.x * (h10 ? -bO : bO);      // partner q^1 (e10 flip)
        const float w2 = phX * aX;                     // partner q^2 (e11 flip)
        const float w3 = phX * (h10 ? -bX : bX);       // partner q^3 (both flip)
        const int q1 = q ^ 1, q2 = q ^ 2, q3 = q ^ 3;

        #pragma unroll
        for (int r = 0; r < 2; ++r)
            #pragma unroll
            for (int j = 0; j < 4; ++j) xch[r][q][j][lane] = v[r][j];
        __syncthreads();
        #pragma unroll
        for (int r = 0; r < 2; ++r)
            #pragma unroll
            for (int j = 0; j < 4; ++j) {
                float4 e1 = xch[r][q1][j][lane];
                float4 e2 = xch[r][q2][j][lane];
                float4 e3 = xch[r][q3][j][lane];
                float4 a;
                a.x = fmaf(w3, e3.x, fmaf(w2, e2.x, fmaf(w1, e1.x, w0 * v[r][j].x)));
                a.y = fmaf(w3, e3.y, fmaf(w2, e2.y, fmaf(w1, e1.y, w0 * v[r][j].y)));
                a.z = fmaf(w3, e3.z, fmaf(w2, e2.z, fmaf(w1, e1.z, w0 * v[r][j].z)));
                a.w = fmaf(w3, e3.w, fmaf(w2, e2.w, fmaf(w1, e1.w, w0 * v[r][j].w)));
                v[r][j] = a;
            }
    }

    #pragma unroll
    for (int j = 0; j < 4; ++j) or0[64 * j + lane] = v[0][j];
    #pragma unroll
    for (int j = 0; j < 4; ++j) or1[64 * j + lane] = v[1][j];
}

__global__ void pack_ab_kernel(const float* __restrict__ af,
                               const float* __restrict__ bf,
                               float2* __restrict__ ab) {
    int i = blockIdx.x * 256 + threadIdx.x;
    if (i < DIM - 1) ab[i] = make_float2(af[i], bf[i]);
}

extern "C" void kernel_launch(void* const* d_in, const int* in_sizes, int n_in,
                              void* d_out, int out_size, void* d_ws, size_t ws_size,
                              hipStream_t stream) {
    const float* x  = (const float*)d_in[0];
    const float* af = (const float*)d_in[1];
    const float* bf = (const float*)d_in[2];
    float* out      = (float*)d_out;

    const bool packed = (d_ws != nullptr) && (ws_size >= (size_t)(DIM - 1) * sizeof(float2));
    if (packed) {
        float2* ab = (float2*)d_ws;
        hipLaunchKernelGGL(pack_ab_kernel, dim3(16), dim3(256), 0, stream, af, bf, ab);
        hipLaunchKernelGGL((bfly_kernel<true>),  dim3(BATCH / 2), dim3(256), 0, stream,
                           x, af, bf, ab, out);
    } else {
        hipLaunchKernelGGL((bfly_kernel<false>), dim3(BATCH / 2), dim3(256), 0, stream,
                           x, af, bf, nullptr, out);
    }
}

// Round 5
// 67.236 us; speedup vs baseline: 2.7178x; 2.7178x over previous
//
#include <hip/hip_runtime.h>

#define DIM   4096
#define BATCH 8192
#define LDSR  68   // padded LDS row stride (floats): 272 B rows, 16B-aligned, conflict-free

// One wave (64 threads) per row.
// Layout A: lane holds e = 64*lane + m, m=0..63, as 16 float4 (v[j] = f[4j..4j+3]).
//   Layers L0..L5 (bs=1..32) are within-thread register FMAs.
// Transpose via wave-private LDS (write f[m] -> xch[m*LDSR+lane]; read row lane).
// Layout B: lane holds e = 64*m' + lane, m'=0..63 (v[j].k = m'=4j+k).
//   Layers L6..L11 (bs=64..2048) are within-thread FMAs with wave-uniform coeffs.
// Coeff index for layer L: c = (4096 - (4096>>L)) + (e >> (L+1)).
// R1/R3 lesson: no __launch_bounds__ min-waves arg; never force the allocator.

__device__ __forceinline__ void rot2(float& lo, float& hi, float a, float b) {
    float l = lo, h = hi;
    lo = fmaf(a, l,  b * h);   // top =  a*x0 + b*x1
    hi = fmaf(a, h, -b * l);   // bot = -b*x0 + a*x1
}
__device__ __forceinline__ void rot4(float4& lo, float4& hi, float a, float b) {
    rot2(lo.x, hi.x, a, b); rot2(lo.y, hi.y, a, b);
    rot2(lo.z, hi.z, a, b); rot2(lo.w, hi.w, a, b);
}

// Quad of coeffs = float2 pairs {2i, 2i+1} as (a0,b0,a1,b1).
template<bool P>
__device__ __forceinline__ float4 loadQ(const float* __restrict__ af,
                                        const float* __restrict__ bf,
                                        const float4* __restrict__ ab4, int i) {
    if constexpr (P) return ab4[i];
    else {
        float2 A = *reinterpret_cast<const float2*>(af + 2 * i);
        float2 B = *reinterpret_cast<const float2*>(bf + 2 * i);
        return make_float4(A.x, B.x, A.y, B.y);
    }
}
template<bool P>
__device__ __forceinline__ float2 loadP(const float* __restrict__ af,
                                        const float* __restrict__ bf,
                                        const float2* __restrict__ ab, int c) {
    if constexpr (P) return ab[c];
    else return make_float2(af[c], bf[c]);
}

template<bool PACKED>
__global__ __launch_bounds__(64)
void bfly_kernel(const float* __restrict__ x,
                 const float* __restrict__ af,
                 const float* __restrict__ bf,
                 const float2* __restrict__ ab,
                 float* __restrict__ out) {
    const int lane = threadIdx.x;                 // 0..63, one wave per block
    const size_t row = blockIdx.x;
    const float4* __restrict__ ab4 = reinterpret_cast<const float4*>(ab);
    const float4* __restrict__ xr  = reinterpret_cast<const float4*>(x + row * DIM);
    float* __restrict__ orow = out + row * DIM;

    __shared__ float xch[64 * LDSR];              // 17408 B, wave-private

    float4 v[16];
    #pragma unroll
    for (int j = 0; j < 16; ++j) v[j] = xr[16 * lane + j];

    // ---- L0 (bs=1): (f[4j],f[4j+1]) c=32l+2j ; (f[4j+2],f[4j+3]) c=32l+2j+1 ----
    #pragma unroll
    for (int j = 0; j < 16; ++j) {
        float4 q = loadQ<PACKED>(af, bf, ab4, 16 * lane + j);
        rot2(v[j].x, v[j].y, q.x, q.y);
        rot2(v[j].z, v[j].w, q.z, q.w);
    }
    // ---- L1 (bs=2): (x,z),(y,w) of v[j]; c = 2048 + 16l + j ----
    #pragma unroll
    for (int s = 0; s < 8; ++s) {
        float4 q = loadQ<PACKED>(af, bf, ab4, 1024 + 8 * lane + s);
        rot2(v[2*s].x,   v[2*s].z,   q.x, q.y);
        rot2(v[2*s].y,   v[2*s].w,   q.x, q.y);
        rot2(v[2*s+1].x, v[2*s+1].z, q.z, q.w);
        rot2(v[2*s+1].y, v[2*s+1].w, q.z, q.w);
    }
    // ---- L2 (bs=4): pairs (v[2s], v[2s+1]) componentwise; c = 3072 + 8l + s ----
    #pragma unroll
    for (int u = 0; u < 4; ++u) {
        float4 q = loadQ<PACKED>(af, bf, ab4, 1536 + 4 * lane + u);
        rot4(v[4*u],     v[4*u + 1], q.x, q.y);
        rot4(v[4*u + 2], v[4*u + 3], q.z, q.w);
    }
    // ---- L3 (bs=8): pairs (v[4u+t], v[4u+t+2]), t=0,1; c = 3584 + 4l + u ----
    #pragma unroll
    for (int w = 0; w < 2; ++w) {
        float4 q = loadQ<PACKED>(af, bf, ab4, 1792 + 2 * lane + w);
        rot4(v[8*w],     v[8*w + 2], q.x, q.y);
        rot4(v[8*w + 1], v[8*w + 3], q.x, q.y);
        rot4(v[8*w + 4], v[8*w + 6], q.z, q.w);
        rot4(v[8*w + 5], v[8*w + 7], q.z, q.w);
    }
    // ---- L4 (bs=16): pairs (v[8w+t], v[8w+t+4]), t=0..3; c = 3840 + 2l + w ----
    {
        float4 q = loadQ<PACKED>(af, bf, ab4, 1920 + lane);
        #pragma unroll
        for (int t = 0; t < 4; ++t) {
            rot4(v[t],     v[t + 4],  q.x, q.y);
            rot4(v[8 + t], v[12 + t], q.z, q.w);
        }
    }
    // ---- L5 (bs=32): pairs (v[t], v[t+8]), t=0..7; c = 3968 + l ----
    {
        float2 p = loadP<PACKED>(af, bf, ab, 3968 + lane);
        #pragma unroll
        for (int t = 0; t < 8; ++t) rot4(v[t], v[t + 8], p.x, p.y);
    }

    // ---- Transpose A->B: write f[m]=v[m>>2].comp(m&3) to xch[m*LDSR + lane] ----
    #pragma unroll
    for (int j = 0; j < 16; ++j) {
        xch[(4*j + 0) * LDSR + lane] = v[j].x;
        xch[(4*j + 1) * LDSR + lane] = v[j].y;
        xch[(4*j + 2) * LDSR + lane] = v[j].z;
        xch[(4*j + 3) * LDSR + lane] = v[j].w;
    }
    __syncthreads();   // 1-wave block: compiles to waitcnt (+barrier), cheap
    #pragma unroll
    for (int j = 0; j < 16; ++j)
        v[j] = *reinterpret_cast<const float4*>(&xch[lane * LDSR + 4 * j]);
    // now v[j].k = element e = 64*(4j+k) + lane

    // ---- L6 (bs=64): (x,y),(z,w); c = 4032 + 2j (+1) — wave-uniform ----
    #pragma unroll
    for (int j = 0; j < 16; ++j) {
        float4 q = loadQ<PACKED>(af, bf, ab4, 2016 + j);
        rot2(v[j].x, v[j].y, q.x, q.y);
        rot2(v[j].z, v[j].w, q.z, q.w);
    }
    // ---- L7 (bs=128): (x,z),(y,w); c = 4064 + j — uniform ----
    #pragma unroll
    for (int s = 0; s < 8; ++s) {
        float4 q = loadQ<PACKED>(af, bf, ab4, 2032 + s);
        rot2(v[2*s].x,   v[2*s].z,   q.x, q.y);
        rot2(v[2*s].y,   v[2*s].w,   q.x, q.y);
        rot2(v[2*s+1].x, v[2*s+1].z, q.z, q.w);
        rot2(v[2*s+1].y, v[2*s+1].w, q.z, q.w);
    }
    // ---- L8 (bs=256): (v[2s], v[2s+1]); c = 4080 + s — uniform ----
    #pragma unroll
    for (int u = 0; u < 4; ++u) {
        float4 q = loadQ<PACKED>(af, bf, ab4, 2040 + u);
        rot4(v[4*u],     v[4*u + 1], q.x, q.y);
        rot4(v[4*u + 2], v[4*u + 3], q.z, q.w);
    }
    // ---- L9 (bs=512): (v[4u+t], v[4u+t+2]); c = 4088 + u — uniform ----
    #pragma unroll
    for (int w = 0; w < 2; ++w) {
        float4 q = loadQ<PACKED>(af, bf, ab4, 2044 + w);
        rot4(v[8*w],     v[8*w + 2], q.x, q.y);
        rot4(v[8*w + 1], v[8*w + 3], q.x, q.y);
        rot4(v[8*w + 4], v[8*w + 6], q.z, q.w);
        rot4(v[8*w + 5], v[8*w + 7], q.z, q.w);
    }
    // ---- L10 (bs=1024): (v[8w+t], v[8w+t+4]); c = 4092 + w — uniform ----
    {
        float4 q = loadQ<PACKED>(af, bf, ab4, 2046);
        #pragma unroll
        for (int t = 0; t < 4; ++t) {
            rot4(v[t],     v[t + 4],  q.x, q.y);
            rot4(v[8 + t], v[12 + t], q.z, q.w);
        }
    }
    // ---- L11 (bs=2048): (v[t], v[t+8]); c = 4094 — uniform ----
    {
        float2 p = loadP<PACKED>(af, bf, ab, 4094);
        #pragma unroll
        for (int t = 0; t < 8; ++t) rot4(v[t], v[t + 8], p.x, p.y);
    }

    // ---- Store: f[m'] -> out[row*DIM + 64*m' + lane], coalesced dwords ----
    #pragma unroll
    for (int j = 0; j < 16; ++j) {
        orow[(4*j + 0) * 64 + lane] = v[j].x;
        orow[(4*j + 1) * 64 + lane] = v[j].y;
        orow[(4*j + 2) * 64 + lane] = v[j].z;
        orow[(4*j + 3) * 64 + lane] = v[j].w;
    }
}

__global__ void pack_ab_kernel(const float* __restrict__ af,
                               const float* __restrict__ bf,
                               float2* __restrict__ ab) {
    int i = blockIdx.x * 256 + threadIdx.x;
    if (i < DIM - 1) ab[i] = make_float2(af[i], bf[i]);
}

extern "C" void kernel_launch(void* const* d_in, const int* in_sizes, int n_in,
                              void* d_out, int out_size, void* d_ws, size_t ws_size,
                              hipStream_t stream) {
    const float* x  = (const float*)d_in[0];
    const float* af = (const float*)d_in[1];
    const float* bf = (const float*)d_in[2];
    float* out      = (float*)d_out;

    const bool packed = (d_ws != nullptr) && (ws_size >= (size_t)(DIM - 1) * sizeof(float2));
    if (packed) {
        float2* ab = (float2*)d_ws;
        hipLaunchKernelGGL(pack_ab_kernel, dim3(16), dim3(256), 0, stream, af, bf, ab);
        hipLaunchKernelGGL((bfly_kernel<true>),  dim3(BATCH), dim3(64), 0, stream,
                           x, af, bf, ab, out);
    } else {
        hipLaunchKernelGGL((bfly_kernel<false>), dim3(BATCH), dim3(64), 0, stream,
                           x, af, bf, nullptr, out);
    }
}

// Round 6
// 66.795 us; speedup vs baseline: 2.7357x; 1.0066x over previous
//
#include <hip/hip_runtime.h>

#define DIM   4096
#define BATCH 8192

// One row per 128-thread block (2 waves). Wave w = e{11} (row half).
// Stage 1: lane l = e{5..10}, reg r = e{0..4}  (32 el = 8 float4, v[j].i, r=4j+i)
//   -> L0..L4 all in-register.
// Transpose T1 (wave-private 8KB tile, XOR-swizzled f4 addressing, no pad):
//   write b128 at f4-addr 8*l + (j ^ (l&7))  (2-way on b128 quarter-phase = free)
//   read  b32, provably conflict-free (bank = 4*(l'{2..4}^r'&7) + l'{0,1}).
// Stage 2: lane l' = e{0..4} | e{10}<<5, reg r' = e{5..9} (nv[j2].k, r'=4j2+k)
//   -> L5..L9 in-register; L10 (e{10}=lane bit 5) via __shfl_xor 32;
//      L11 (e{11}=wave) via one cross-wave tile exchange + the ONE barrier.
// Coeff index layer L: c = (4096 - (1<<(12-L))) + (e >> (L+1)).
// R1/R3 lesson: no min-waves launch bound; watch WRITE_SIZE==131072 for spill.

__device__ __forceinline__ void rot2(float& lo, float& hi, float a, float b) {
    float l = lo, h = hi;
    lo = fmaf(a, l,  b * h);   // top =  a*x0 + b*x1
    hi = fmaf(a, h, -b * l);   // bot = -b*x0 + a*x1
}
__device__ __forceinline__ void rot4(float4& lo, float4& hi, float a, float b) {
    rot2(lo.x, hi.x, a, b); rot2(lo.y, hi.y, a, b);
    rot2(lo.z, hi.z, a, b); rot2(lo.w, hi.w, a, b);
}

// Pair-quad of coeffs {2i, 2i+1} as (a0,b0,a1,b1).
template<bool P>
__device__ __forceinline__ float4 loadQ(const float* __restrict__ af,
                                        const float* __restrict__ bf,
                                        const float4* __restrict__ ab4, int i) {
    if constexpr (P) return ab4[i];
    else {
        float2 A = *reinterpret_cast<const float2*>(af + 2 * i);
        float2 B = *reinterpret_cast<const float2*>(bf + 2 * i);
        return make_float4(A.x, B.x, A.y, B.y);
    }
}
template<bool P>
__device__ __forceinline__ float2 loadP(const float* __restrict__ af,
                                        const float* __restrict__ bf,
                                        const float2* __restrict__ ab, int c) {
    if constexpr (P) return ab[c];
    else return make_float2(af[c], bf[c]);
}

template<bool PACKED>
__global__ __launch_bounds__(128)
void bfly_kernel(const float* __restrict__ x,
                 const float* __restrict__ af,
                 const float* __restrict__ bf,
                 const float2* __restrict__ ab,
                 float* __restrict__ out) {
    const int tid = threadIdx.x;
    const int l   = tid & 63;    // lane
    const int w   = tid >> 6;    // wave = e{11}
    const size_t row = blockIdx.x;

    const float4* __restrict__ ab4 = reinterpret_cast<const float4*>(ab);
    const float4* __restrict__ xr  = reinterpret_cast<const float4*>(x + row * DIM);
    float* __restrict__ orow = out + row * DIM;

    __shared__ float tile[2][2048];   // 16 KB total, tile[w] is wave-private
    float* __restrict__ T = tile[w];

    // ---- Load stage-1: v[j] = elements e = 2048w + 32l + 4j..4j+3 ----
    float4 v[8];
    #pragma unroll
    for (int j = 0; j < 8; ++j) v[j] = xr[w * 512 + l * 8 + j];

    // ---- L0 (bs=1): (x,y),(z,w); c = 1024w + 16l + 2j (+1) ----
    #pragma unroll
    for (int j = 0; j < 8; ++j) {
        float4 q = loadQ<PACKED>(af, bf, ab4, w * 512 + 8 * l + j);
        rot2(v[j].x, v[j].y, q.x, q.y);
        rot2(v[j].z, v[j].w, q.z, q.w);
    }
    // ---- L1 (bs=2): (x,z),(y,w); c = 2048 + 512w + 8l + j ----
    #pragma unroll
    for (int j = 0; j < 8; ++j) {
        float2 p = loadP<PACKED>(af, bf, ab, 2048 + 512 * w + 8 * l + j);
        rot2(v[j].x, v[j].z, p.x, p.y);
        rot2(v[j].y, v[j].w, p.x, p.y);
    }
    // ---- L2 (bs=4): (v[2u], v[2u+1]); c = 3072 + 256w + 4l + u ----
    #pragma unroll
    for (int u = 0; u < 4; ++u) {
        float2 p = loadP<PACKED>(af, bf, ab, 3072 + 256 * w + 4 * l + u);
        rot4(v[2*u], v[2*u + 1], p.x, p.y);
    }
    // ---- L3 (bs=8): (v[4g+t], v[4g+t+2]); c = 3584 + 128w + 2l + g ----
    #pragma unroll
    for (int g = 0; g < 2; ++g) {
        float2 p = loadP<PACKED>(af, bf, ab, 3584 + 128 * w + 2 * l + g);
        rot4(v[4*g],     v[4*g + 2], p.x, p.y);
        rot4(v[4*g + 1], v[4*g + 3], p.x, p.y);
    }
    // ---- L4 (bs=16): (v[t], v[t+4]); c = 3840 + 64w + l ----
    {
        float2 p = loadP<PACKED>(af, bf, ab, 3840 + 64 * w + l);
        #pragma unroll
        for (int t = 0; t < 4; ++t) rot4(v[t], v[t + 4], p.x, p.y);
    }

    // ---- T1 write: v[j] -> f4 addr 8l + (j ^ (l&7)) (b128, swizzled) ----
    #pragma unroll
    for (int j = 0; j < 8; ++j)
        *reinterpret_cast<float4*>(&T[(8 * l + (j ^ (l & 7))) * 4]) = v[j];

    __syncthreads();   // (intra-wave ordering suffices for T1, but barrier is cheap+safe)

    // ---- T1 read: stage-2 nv[j2].k = element e = 2048w + 1024h10 + 32(4j2+k) + low5 ----
    const int h10 = l >> 5, low5 = l & 31;
    const int oj = (l >> 2) & 7, oi = l & 3;
    float4 nv[8];
    #pragma unroll
    for (int j2 = 0; j2 < 8; ++j2) {
        float t0, t1, t2, t3;
        {int rp=4*j2+0; t0 = T[(8*(rp|(h10<<5)) + (oj ^ (rp&7)))*4 + oi];}
        {int rp=4*j2+1; t1 = T[(8*(rp|(h10<<5)) + (oj ^ (rp&7)))*4 + oi];}
        {int rp=4*j2+2; t2 = T[(8*(rp|(h10<<5)) + (oj ^ (rp&7)))*4 + oi];}
        {int rp=4*j2+3; t3 = T[(8*(rp|(h10<<5)) + (oj ^ (rp&7)))*4 + oi];}
        nv[j2] = make_float4(t0, t1, t2, t3);
    }

    // ---- L5 (bs=32): (x,y),(z,w); c = 3968 + 32w + 16h10 + 2j2 (+1) ----
    #pragma unroll
    for (int j2 = 0; j2 < 8; ++j2) {
        float4 q = loadQ<PACKED>(af, bf, ab4, 1984 + 16 * w + 8 * h10 + j2);
        rot2(nv[j2].x, nv[j2].y, q.x, q.y);
        rot2(nv[j2].z, nv[j2].w, q.z, q.w);
    }
    // ---- L6 (bs=64): (x,z),(y,w); c = 4032 + 16w + 8h10 + j2 ----
    #pragma unroll
    for (int j2 = 0; j2 < 8; ++j2) {
        float2 p = loadP<PACKED>(af, bf, ab, 4032 + 16 * w + 8 * h10 + j2);
        rot2(nv[j2].x, nv[j2].z, p.x, p.y);
        rot2(nv[j2].y, nv[j2].w, p.x, p.y);
    }
    // ---- L7 (bs=128): (nv[2u], nv[2u+1]); c = 4064 + 8w + 4h10 + u ----
    #pragma unroll
    for (int u = 0; u < 4; ++u) {
        float2 p = loadP<PACKED>(af, bf, ab, 4064 + 8 * w + 4 * h10 + u);
        rot4(nv[2*u], nv[2*u + 1], p.x, p.y);
    }
    // ---- L8 (bs=256): (nv[4g+t], nv[4g+t+2]); c = 4080 + 4w + 2h10 + g ----
    #pragma unroll
    for (int g = 0; g < 2; ++g) {
        float2 p = loadP<PACKED>(af, bf, ab, 4080 + 4 * w + 2 * h10 + g);
        rot4(nv[4*g],     nv[4*g + 2], p.x, p.y);
        rot4(nv[4*g + 1], nv[4*g + 3], p.x, p.y);
    }
    // ---- L9 (bs=512): (nv[t], nv[t+4]); c = 4088 + 2w + h10 ----
    {
        float2 p = loadP<PACKED>(af, bf, ab, 4088 + 2 * w + h10);
        #pragma unroll
        for (int t = 0; t < 4; ++t) rot4(nv[t], nv[t + 4], p.x, p.y);
    }
    // ---- L10 (bs=1024): partner lane l^32; c = 4092 + w ----
    {
        float2 p = loadP<PACKED>(af, bf, ab, 4092 + w);
        const float sb = (l & 32) ? -p.y : p.y;
        #pragma unroll
        for (int j2 = 0; j2 < 8; ++j2) {
            nv[j2].x = fmaf(p.x, nv[j2].x, sb * __shfl_xor(nv[j2].x, 32, 64));
            nv[j2].y = fmaf(p.x, nv[j2].y, sb * __shfl_xor(nv[j2].y, 32, 64));
            nv[j2].z = fmaf(p.x, nv[j2].z, sb * __shfl_xor(nv[j2].z, 32, 64));
            nv[j2].w = fmaf(p.x, nv[j2].w, sb * __shfl_xor(nv[j2].w, 32, 64));
        }
    }
    // ---- L11 (bs=2048): cross-wave exchange via tiles; c = 4094 ----
    {
        float2 p = loadP<PACKED>(af, bf, ab, 4094);
        const float sb = w ? -p.y : p.y;
        #pragma unroll
        for (int j2 = 0; j2 < 8; ++j2)
            *reinterpret_cast<float4*>(&T[(8 * l + (j2 ^ (l & 7))) * 4]) = nv[j2];
        __syncthreads();
        const float* __restrict__ Tp = tile[w ^ 1];
        #pragma unroll
        for (int j2 = 0; j2 < 8; ++j2) {
            float4 pv = *reinterpret_cast<const float4*>(&Tp[(8 * l + (j2 ^ (l & 7))) * 4]);
            nv[j2].x = fmaf(p.x, nv[j2].x, sb * pv.x);
            nv[j2].y = fmaf(p.x, nv[j2].y, sb * pv.y);
            nv[j2].z = fmaf(p.x, nv[j2].z, sb * pv.z);
            nv[j2].w = fmaf(p.x, nv[j2].w, sb * pv.w);
        }
    }

    // ---- Store: e = 2048w + 1024h10 + 32(4j2+k) + low5 (2x128B-coalesced dwords) ----
    const int sbase = 2048 * w + 1024 * h10 + low5;
    #pragma unroll
    for (int j2 = 0; j2 < 8; ++j2) {
        orow[sbase + 32 * (4*j2 + 0)] = nv[j2].x;
        orow[sbase + 32 * (4*j2 + 1)] = nv[j2].y;
        orow[sbase + 32 * (4*j2 + 2)] = nv[j2].z;
        orow[sbase + 32 * (4*j2 + 3)] = nv[j2].w;
    }
}

__global__ void pack_ab_kernel(const float* __restrict__ af,
                               const float* __restrict__ bf,
                               float2* __restrict__ ab) {
    int i = blockIdx.x * 256 + threadIdx.x;
    if (i < DIM - 1) ab[i] = make_float2(af[i], bf[i]);
}

extern "C" void kernel_launch(void* const* d_in, const int* in_sizes, int n_in,
                              void* d_out, int out_size, void* d_ws, size_t ws_size,
                              hipStream_t stream) {
    const float* x  = (const float*)d_in[0];
    const float* af = (const float*)d_in[1];
    const float* bf = (const float*)d_in[2];
    float* out      = (float*)d_out;

    const bool packed = (d_ws != nullptr) && (ws_size >= (size_t)(DIM - 1) * sizeof(float2));
    if (packed) {
        float2* ab = (float2*)d_ws;
        hipLaunchKernelGGL(pack_ab_kernel, dim3(16), dim3(256), 0, stream, af, bf, ab);
        hipLaunchKernelGGL((bfly_kernel<true>),  dim3(BATCH), dim3(128), 0, stream,
                           x, af, bf, ab, out);
    } else {
        hipLaunchKernelGGL((bfly_kernel<false>), dim3(BATCH), dim3(128), 0, stream,
                           x, af, bf, nullptr, out);
    }
}

// Round 7
// 56.420 us; speedup vs baseline: 3.2388x; 1.1839x over previous
//
#include <hip/hip_runtime.h>

#define DIM   4096
#define BATCH 8192
// One row per 256-thread block (R2 structure, validated). Wave q owns quarter
// [1024q, 1024q+1024); thread lane holds e = 1024q + 256j + 4*lane + i (j,i=0..3).
// Layer L pairs e with e^(1<<L); coeff index c = (4096 - (4096>>L)) + (e >> (L+1)).
//   L0..L1  : within float4 (i axis)        — register FMAs
//   L2..L7  : lane xor 1,2,4,8,16,32        — DPP quad_perm (1,2), ds_swizzle (4,16),
//                                             DPP row_ror:8 (8), permlane32_swap (32)
//             -> shuffles moved OFF the shared per-CU LDS pipe onto VALU.
//   L8..L9  : register index j distance 1,2 — register FMAs
//   L10+L11 : cross-wave, FUSED 4-source combine (R3-verified algebra), ONE barrier.
// R1/R3 lesson: VGPR cap must exceed working set (~45) — (256,7) caps at ~73.

#if defined(__has_builtin)
#  if __has_builtin(__builtin_amdgcn_permlane32_swap)
#    define HAVE_PL32 1
#  endif
#endif
#ifndef HAVE_PL32
#  define HAVE_PL32 0
#endif

__device__ __forceinline__ void rot2(float& lo, float& hi, float a, float b) {
    float l = lo, h = hi;
    lo = fmaf(a, l,  b * h);   // top =  a*x0 + b*x1
    hi = fmaf(a, h, -b * l);   // bot = -b*x0 + a*x1
}

template<bool PACKED>
__device__ __forceinline__ float2 coef(const float* __restrict__ af,
                                       const float* __restrict__ bf,
                                       const float2* __restrict__ ab, int c) {
    if constexpr (PACKED) return ab[c];
    else                  return make_float2(af[c], bf[c]);
}

// Cross-lane xor-M partner fetch, fastest available pipe per M.
template<int M>
__device__ __forceinline__ float pxor(float x, bool hi) {
    int xi = __float_as_int(x);
    if constexpr (M == 1)        // quad_perm [1,0,3,2]
        return __int_as_float(__builtin_amdgcn_update_dpp(0, xi, 0xB1, 0xF, 0xF, true));
    else if constexpr (M == 2)   // quad_perm [2,3,0,1]
        return __int_as_float(__builtin_amdgcn_update_dpp(0, xi, 0x4E, 0xF, 0xF, true));
    else if constexpr (M == 4)   // ds_swizzle BitMode xor 4
        return __int_as_float(__builtin_amdgcn_ds_swizzle(xi, 0x101F));
    else if constexpr (M == 8)   // row_ror:8 within row-of-16 == xor 8
        return __int_as_float(__builtin_amdgcn_update_dpp(0, xi, 0x128, 0xF, 0xF, true));
    else if constexpr (M == 16)  // ds_swizzle BitMode xor 16 (within 32-halves)
        return __int_as_float(__builtin_amdgcn_ds_swizzle(xi, 0x401F));
    else {                       // M == 32: crosses 32-lane halves
#if HAVE_PL32
        unsigned xu = (unsigned)xi;
        auto r = __builtin_amdgcn_permlane32_swap(xu, xu, false, false);
        // r[0] = {x[0:31], x[0:31]}, r[1] = {x[32:63], x[32:63]}
        return __uint_as_float(hi ? r[0] : r[1]);
#else
        return __shfl_xor(x, 32, 64);
#endif
    }
}

template<int M, int JSH, int LSH, bool PACKED>
__device__ __forceinline__ void shuf_layer(float4 (&v)[4], int lane, int base,
                                           const float* __restrict__ af,
                                           const float* __restrict__ bf,
                                           const float2* __restrict__ ab) {
    const bool hi = (lane & M) != 0;
    #pragma unroll
    for (int j = 0; j < 4; ++j) {
        const int c = base + (j << JSH) + (lane >> LSH);
        float2 p = coef<PACKED>(af, bf, ab, c);
        const float sb = hi ? -p.y : p.y;   // top: +b*partner ; bot: -b*partner
        v[j].x = fmaf(p.x, v[j].x, sb * pxor<M>(v[j].x, hi));
        v[j].y = fmaf(p.x, v[j].y, sb * pxor<M>(v[j].y, hi));
        v[j].z = fmaf(p.x, v[j].z, sb * pxor<M>(v[j].z, hi));
        v[j].w = fmaf(p.x, v[j].w, sb * pxor<M>(v[j].w, hi));
    }
}

template<bool PACKED>
__global__ __launch_bounds__(256, 7)
void bfly_kernel(const float* __restrict__ x,
                 const float* __restrict__ af,
                 const float* __restrict__ bf,
                 const float2* __restrict__ ab,
                 float* __restrict__ out) {
    const int lane = threadIdx.x & 63;
    const int q    = threadIdx.x >> 6;     // wave index = row quarter
    const size_t row = blockIdx.x;

    const float4* __restrict__ xr = reinterpret_cast<const float4*>(x + row * DIM) + q * 256;
    float4* __restrict__ orow     = reinterpret_cast<float4*>(out + row * DIM) + q * 256;

    __shared__ float4 xch[4][4][64];   // [wave][j][lane] = 16 KB

    float4 v[4];
    #pragma unroll
    for (int j = 0; j < 4; ++j) v[j] = xr[64 * j + lane];

    // ---- L0 (bs=1): pairs (x,y),(z,w); c0 = 512q + 128j + 2*lane, c0+1 ----
    #pragma unroll
    for (int j = 0; j < 4; ++j) {
        float a0, b0, a1, b1;
        if constexpr (PACKED) {
            float4 p = reinterpret_cast<const float4*>(ab)[q * 256 + 64 * j + lane];
            a0 = p.x; b0 = p.y; a1 = p.z; b1 = p.w;
        } else {
            const int c = 512 * q + 128 * j + 2 * lane;
            float2 aa = *reinterpret_cast<const float2*>(af + c);
            float2 bb = *reinterpret_cast<const float2*>(bf + c);
            a0 = aa.x; b0 = bb.x; a1 = aa.y; b1 = bb.y;
        }
        rot2(v[j].x, v[j].y, a0, b0);
        rot2(v[j].z, v[j].w, a1, b1);
    }

    // ---- L1 (bs=2): pairs (x,z),(y,w); c = 2048 + 256q + 64j + lane ----
    #pragma unroll
    for (int j = 0; j < 4; ++j) {
        float2 p = coef<PACKED>(af, bf, ab, 2048 + 256 * q + 64 * j + lane);
        rot2(v[j].x, v[j].z, p.x, p.y);
        rot2(v[j].y, v[j].w, p.x, p.y);
    }

    // ---- L2..L7: cross-lane layers (DPP / swizzle / permlane) ----
    shuf_layer< 1, 5, 1, PACKED>(v, lane, 3072 + 128 * q, af, bf, ab);  // bs=4
    shuf_layer< 2, 4, 2, PACKED>(v, lane, 3584 +  64 * q, af, bf, ab);  // bs=8
    shuf_layer< 4, 3, 3, PACKED>(v, lane, 3840 +  32 * q, af, bf, ab);  // bs=16
    shuf_layer< 8, 2, 4, PACKED>(v, lane, 3968 +  16 * q, af, bf, ab);  // bs=32
    shuf_layer<16, 1, 5, PACKED>(v, lane, 4032 +   8 * q, af, bf, ab);  // bs=64
    shuf_layer<32, 0, 6, PACKED>(v, lane, 4064 +   4 * q, af, bf, ab);  // bs=128

    // ---- L8 (bs=256): pairs (0,1),(2,3); c = 4080 + 2q + k ----
    #pragma unroll
    for (int k = 0; k < 2; ++k) {
        float2 p = coef<PACKED>(af, bf, ab, 4080 + 2 * q + k);
        rot2(v[2*k].x, v[2*k+1].x, p.x, p.y);
        rot2(v[2*k].y, v[2*k+1].y, p.x, p.y);
        rot2(v[2*k].z, v[2*k+1].z, p.x, p.y);
        rot2(v[2*k].w, v[2*k+1].w, p.x, p.y);
    }
    // ---- L9 (bs=512): pairs (0,2),(1,3); c = 4088 + q ----
    {
        float2 p = coef<PACKED>(af, bf, ab, 4088 + q);
        #pragma unroll
        for (int j = 0; j < 2; ++j) {
            rot2(v[j].x, v[j+2].x, p.x, p.y);
            rot2(v[j].y, v[j+2].y, p.x, p.y);
            rot2(v[j].z, v[j+2].z, p.x, p.y);
            rot2(v[j].w, v[j+2].w, p.x, p.y);
        }
    }

    // ---- L10+L11 fused: one 4-source combine across waves, ONE barrier ----
    // (R3-verified algebra.) u = w0*v + w1*v(q^1) + w2*v(q^2) + w3*v(q^3).
    {
        float2 c0 = coef<PACKED>(af, bf, ab, 4092);   // (a,b) for e11=0
        float2 c1 = coef<PACKED>(af, bf, ab, 4093);   // (a,b) for e11=1
        float2 c2 = coef<PACKED>(af, bf, ab, 4094);   // (A,B)
        const int h11 = q >> 1, h10 = q & 1;
        const float aO = h11 ? c1.x : c0.x, bO = h11 ? c1.y : c0.y;
        const float aX = h11 ? c0.x : c1.x, bX = h11 ? c0.y : c1.y;
        const float phX = h11 ? -c2.y : c2.y;
        const float w0 = c2.x * aO;
        const float w1 = c2.x * (h10 ? -bO : bO);
        const float w2 = phX * aX;
        const float w3 = phX * (h10 ? -bX : bX);
        const int q1 = q ^ 1, q2 = q ^ 2, q3 = q ^ 3;

        #pragma unroll
        for (int j = 0; j < 4; ++j) xch[q][j][lane] = v[j];
        __syncthreads();
        #pragma unroll
        for (int j = 0; j < 4; ++j) {
            float4 e1 = xch[q1][j][lane];
            float4 e2 = xch[q2][j][lane];
            float4 e3 = xch[q3][j][lane];
            float4 a;
            a.x = fmaf(w3, e3.x, fmaf(w2, e2.x, fmaf(w1, e1.x, w0 * v[j].x)));
            a.y = fmaf(w3, e3.y, fmaf(w2, e2.y, fmaf(w1, e1.y, w0 * v[j].y)));
            a.z = fmaf(w3, e3.z, fmaf(w2, e2.z, fmaf(w1, e1.z, w0 * v[j].z)));
            a.w = fmaf(w3, e3.w, fmaf(w2, e2.w, fmaf(w1, e1.w, w0 * v[j].w)));
            v[j] = a;
        }
    }

    #pragma unroll
    for (int j = 0; j < 4; ++j) orow[64 * j + lane] = v[j];
}

__global__ void pack_ab_kernel(const float* __restrict__ af,
                               const float* __restrict__ bf,
                               float2* __restrict__ ab) {
    int i = blockIdx.x * 256 + threadIdx.x;
    if (i < DIM - 1) ab[i] = make_float2(af[i], bf[i]);
}

extern "C" void kernel_launch(void* const* d_in, const int* in_sizes, int n_in,
                              void* d_out, int out_size, void* d_ws, size_t ws_size,
                              hipStream_t stream) {
    const float* x  = (const float*)d_in[0];
    const float* af = (const float*)d_in[1];
    const float* bf = (const float*)d_in[2];
    float* out      = (float*)d_out;

    const bool packed = (d_ws != nullptr) && (ws_size >= (size_t)(DIM - 1) * sizeof(float2));
    if (packed) {
        float2* ab = (float2*)d_ws;
        hipLaunchKernelGGL(pack_ab_kernel, dim3(16), dim3(256), 0, stream, af, bf, ab);
        hipLaunchKernelGGL((bfly_kernel<true>),  dim3(BATCH), dim3(256), 0, stream,
                           x, af, bf, ab, out);
    } else {
        hipLaunchKernelGGL((bfly_kernel<false>), dim3(BATCH), dim3(256), 0, stream,
                           x, af, bf, nullptr, out);
    }
}